// Round 1
// baseline (966.463 us; speedup 1.0000x reference)
//
#include <hip/hip_runtime.h>

// Problem: B=2, C=4, D=64, H=256, W=256
// Output scalar = sum_{interior cells, keep} ||omega_p - omega_t||_2 / sum(keep)
// keep = all 27 masks in 3x3x3 neighborhood == 1
// omega components: plain neighbor differences of (pred - targ) channels 1..3
// (SCALES=10 cancels 2*DELTA=10 exactly).

#define D_ 64
#define H_ 256
#define W_ 256

__global__ __launch_bounds__(256) void vort_kernel(
    const float* __restrict__ preds, const float* __restrict__ targs,
    const float* __restrict__ masks, double* __restrict__ acc)
{
    const int w = threadIdx.x;                  // 0..255 (full W row)
    int blk = blockIdx.x;
    const int h = blk % 254 + 1; blk /= 254;    // interior h in [1,254]
    const int d = blk % 62 + 1;  blk /= 62;     // interior d in [1,62]
    const int b = blk;                          // 0..1

    const long long sD = (long long)H_ * W_;        // 65536
    const long long sC = (long long)D_ * H_ * W_;   // 4194304 (mask batch stride too)
    const long long mBase = (long long)b * sC + (long long)d * sD + (long long)h * W_;

    // Stage the 3x3 (d,h) neighborhood of mask rows (full W) in LDS, coalesced.
    __shared__ float sm[9][W_];
    #pragma unroll
    for (int r = 0; r < 9; ++r) {
        const int dd = r / 3 - 1;
        const int dh = r % 3 - 1;
        sm[r][w] = masks[mBase + (long long)dd * sD + (long long)dh * W_ + w];
    }
    __syncthreads();

    float norm = 0.0f, cnt = 0.0f;
    if (w >= 1 && w <= 254) {
        // keep = min over 3x3x3 neighborhood > 0.5
        float mn = 1.0f;
        #pragma unroll
        for (int r = 0; r < 9; ++r) {
            float a = fminf(fminf(sm[r][w - 1], sm[r][w]), sm[r][w + 1]);
            mn = fminf(mn, a);
        }
        if (mn > 0.5f) {
            cnt = 1.0f;
            const long long base = (long long)b * 4 * sC + (long long)d * sD
                                 + (long long)h * W_ + w;
            const float* p1 = preds + base + sC;       // channel 1 (u)
            const float* t1 = targs + base + sC;
            const float* p2 = preds + base + 2 * sC;   // channel 2 (v)
            const float* t2 = targs + base + 2 * sC;
            const float* p3 = preds + base + 3 * sC;   // channel 3 (w)
            const float* t3 = targs + base + 3 * sC;

            // Delta_c at offset o = p_c[o] - t_c[o]; omega = neighbor diffs
            const float d3_hp = p3[ W_] - t3[ W_];
            const float d3_hm = p3[-W_] - t3[-W_];
            const float d2_dp = p2[ sD] - t2[ sD];
            const float d2_dm = p2[-sD] - t2[-sD];
            const float d1_dp = p1[ sD] - t1[ sD];
            const float d1_dm = p1[-sD] - t1[-sD];
            const float d3_wp = p3[  1] - t3[  1];
            const float d3_wm = p3[ -1] - t3[ -1];
            const float d2_wp = p2[  1] - t2[  1];
            const float d2_wm = p2[ -1] - t2[ -1];
            const float d1_hp = p1[ W_] - t1[ W_];
            const float d1_hm = p1[-W_] - t1[-W_];

            const float wx = (d3_hp - d3_hm) - (d2_dp - d2_dm);
            const float wy = (d1_dp - d1_dm) - (d3_wp - d3_wm);
            const float wz = (d2_wp - d2_wm) - (d1_hp - d1_hm);
            norm = sqrtf(wx * wx + wy * wy + wz * wz);
        }
    }

    // wave (64-lane) shuffle reduction
    #pragma unroll
    for (int off = 32; off > 0; off >>= 1) {
        norm += __shfl_down(norm, off, 64);
        cnt  += __shfl_down(cnt,  off, 64);
    }
    __shared__ float ssum[4];
    __shared__ float scnt[4];
    const int lane = threadIdx.x & 63;
    const int wv   = threadIdx.x >> 6;
    if (lane == 0) { ssum[wv] = norm; scnt[wv] = cnt; }
    __syncthreads();
    if (threadIdx.x == 0) {
        const float s = ssum[0] + ssum[1] + ssum[2] + ssum[3];
        const float c = scnt[0] + scnt[1] + scnt[2] + scnt[3];
        atomicAdd(&acc[0], (double)s);
        atomicAdd(&acc[1], (double)c);
    }
}

__global__ void finalize_kernel(const double* __restrict__ acc, float* __restrict__ out)
{
    const double c = acc[1];
    out[0] = (c != 0.0) ? (float)(acc[0] / c) : 0.0f;
}

extern "C" void kernel_launch(void* const* d_in, const int* in_sizes, int n_in,
                              void* d_out, int out_size, void* d_ws, size_t ws_size,
                              hipStream_t stream)
{
    const float* preds = (const float*)d_in[0];
    const float* targs = (const float*)d_in[1];
    const float* masks = (const float*)d_in[2];
    float* out = (float*)d_out;
    double* acc = (double*)d_ws;

    hipMemsetAsync(d_ws, 0, 2 * sizeof(double), stream);

    const int nblocks = 2 * 62 * 254;  // (b, d-1, h-1)
    vort_kernel<<<nblocks, 256, 0, stream>>>(preds, targs, masks, acc);
    finalize_kernel<<<1, 1, 0, stream>>>(acc, out);
}

// Round 2
// 400.186 us; speedup vs baseline: 2.4150x; 2.4150x over previous
//
#include <hip/hip_runtime.h>

// B=2, C=4, D=64, H=256, W=256
// out = sum_{interior, keep} ||omega_p - omega_t||_2 / sum(keep)
// keep = all 27 masks in 3x3x3 neighborhood == 1
// omega components are raw neighbor differences of (pred - targ) ch1..3
// (SCALES=10 cancels 2*DELTA=10). Dense, fully-coalesced float4 streaming:
// R1 post-mortem showed mask-gated scalar loads ran at 458 GB/s (5.7% peak)
// due to sparse-lane scattered transactions; bytes were ~the same either way.

#define SD 65536LL      // d stride = H*W
#define SC 4194304LL    // channel stride = D*H*W

__global__ __launch_bounds__(256) void vort_dense(
    const float* __restrict__ preds, const float* __restrict__ targs,
    const float* __restrict__ masks, double* __restrict__ acc)
{
    const int lane = threadIdx.x & 63;
    const int wv   = threadIdx.x >> 6;
    int blk = blockIdx.x;
    const int tile = blk & 63; blk >>= 6;       // 64 h-tiles of 4 rows
    const int d = blk % 62 + 1; blk /= 62;      // interior d 1..62
    const int b = blk;                          // 0..1
    const int h = 1 + tile * 4 + wv;            // one row per wave
    const int w0 = lane << 2;                   // 4 w per lane, full 256 row

    float norm = 0.0f, cnt = 0.0f;

    if (h <= 254) {   // wave-uniform guard (tile 63 waves 2,3 are out of range)
        // ---- masks: componentwise min over the 9 (d,h) neighbor rows ----
        const long long mbase = (long long)b * SC + (long long)d * SD
                              + (long long)h * 256 + w0;
        float4 M = make_float4(1.f, 1.f, 1.f, 1.f);
        #pragma unroll
        for (int dd = -1; dd <= 1; ++dd)
            #pragma unroll
            for (int dh = -1; dh <= 1; ++dh) {
                float4 mm = *(const float4*)(masks + mbase + (long long)dd * SD
                                             + (long long)dh * 256);
                M.x = fminf(M.x, mm.x); M.y = fminf(M.y, mm.y);
                M.z = fminf(M.z, mm.z); M.w = fminf(M.w, mm.w);
            }

        // ---- velocity diffs: Delta_c = pred_c - targ_c, float4 rows ----
        const long long base1 = ((long long)(b * 4 + 1) * 64 + d) * SD / 64 * 64; // placeholder avoided below
        const long long b1 = ((long long)(b * 4 + 1) * 64 + d) * 65536LL + (long long)h * 256 + w0;
        const long long b2 = ((long long)(b * 4 + 2) * 64 + d) * 65536LL + (long long)h * 256 + w0;
        const long long b3 = ((long long)(b * 4 + 3) * 64 + d) * 65536LL + (long long)h * 256 + w0;
        (void)base1;

        float u_dm[4], u_dp[4], u_hm[4], u_hp[4];
        float v_dm[4], v_dp[4], v_c[4];
        float w_hm[4], w_hp[4], w_c[4];

        #define LOADD(dst, bb, off) { \
            float4 p_ = *(const float4*)(preds + (bb) + (off)); \
            float4 t_ = *(const float4*)(targs + (bb) + (off)); \
            dst[0] = p_.x - t_.x; dst[1] = p_.y - t_.y; \
            dst[2] = p_.z - t_.z; dst[3] = p_.w - t_.w; }

        LOADD(u_dm, b1, -SD);  LOADD(u_dp, b1, +SD);
        LOADD(u_hm, b1, -256); LOADD(u_hp, b1, +256);
        LOADD(v_dm, b2, -SD);  LOADD(v_dp, b2, +SD);  LOADD(v_c, b2, 0);
        LOADD(w_hm, b3, -256); LOADD(w_hp, b3, +256); LOADD(w_c, b3, 0);
        #undef LOADD

        // ---- wave-shuffle edges for w+-1 windows (wave-uniform path) ----
        const float vL = __shfl_up(v_c[3], 1, 64);
        const float vR = __shfl_down(v_c[0], 1, 64);
        const float wL = __shfl_up(w_c[3], 1, 64);
        const float wR = __shfl_down(w_c[0], 1, 64);
        const float ML = __shfl_up(M.w, 1, 64);
        const float MR = __shfl_down(M.x, 1, 64);

        const float vv[6] = { vL, v_c[0], v_c[1], v_c[2], v_c[3], vR };
        const float ww[6] = { wL, w_c[0], w_c[1], w_c[2], w_c[3], wR };
        const float Mm[6] = { ML, M.x, M.y, M.z, M.w, MR };

        #pragma unroll
        for (int j = 0; j < 4; ++j) {
            const int wc = w0 + j;
            const float keepv = fminf(fminf(Mm[j], Mm[j + 1]), Mm[j + 2]);
            const bool valid = (wc >= 1) && (wc <= 254) && (keepv > 0.5f);
            const float wx = (w_hp[j] - w_hm[j]) - (v_dp[j] - v_dm[j]);
            const float wy = (u_dp[j] - u_dm[j]) - (ww[j + 2] - ww[j]);
            const float wz = (vv[j + 2] - vv[j]) - (u_hp[j] - u_hm[j]);
            const float n = sqrtf(wx * wx + wy * wy + wz * wz);
            norm += valid ? n : 0.0f;
            cnt  += valid ? 1.0f : 0.0f;
        }
    }

    // ---- reduction: wave shuffle -> LDS across 4 waves -> global atomic ----
    #pragma unroll
    for (int off = 32; off > 0; off >>= 1) {
        norm += __shfl_down(norm, off, 64);
        cnt  += __shfl_down(cnt,  off, 64);
    }
    __shared__ float ssum[4], scnt[4];
    if (lane == 0) { ssum[wv] = norm; scnt[wv] = cnt; }
    __syncthreads();
    if (threadIdx.x == 0) {
        const float s = ssum[0] + ssum[1] + ssum[2] + ssum[3];
        const float c = scnt[0] + scnt[1] + scnt[2] + scnt[3];
        atomicAdd(&acc[0], (double)s);
        atomicAdd(&acc[1], (double)c);
    }
}

__global__ void finalize_kernel(const double* __restrict__ acc, float* __restrict__ out)
{
    const double c = acc[1];
    out[0] = (c != 0.0) ? (float)(acc[0] / c) : 0.0f;
}

extern "C" void kernel_launch(void* const* d_in, const int* in_sizes, int n_in,
                              void* d_out, int out_size, void* d_ws, size_t ws_size,
                              hipStream_t stream)
{
    const float* preds = (const float*)d_in[0];
    const float* targs = (const float*)d_in[1];
    const float* masks = (const float*)d_in[2];
    float* out = (float*)d_out;
    double* acc = (double*)d_ws;

    hipMemsetAsync(d_ws, 0, 2 * sizeof(double), stream);

    const int nblocks = 2 * 62 * 64;   // (b, d-1, h-tile)
    vort_dense<<<nblocks, 256, 0, stream>>>(preds, targs, masks, acc);
    finalize_kernel<<<1, 1, 0, stream>>>(acc, out);
}

// Round 3
// 398.157 us; speedup vs baseline: 2.4273x; 1.0051x over previous
//
#include <hip/hip_runtime.h>

// B=2, C=4, D=64, H=256, W=256
// out = sum_{interior, keep} ||omega_p - omega_t||_2 / sum(keep)
// keep = all 27 masks in 3x3x3 neighborhood == 1; omega = neighbor diffs of
// (pred - targ) ch1..3 (SCALES=10 cancels 2*DELTA=10).
//
// R2 post-mortem: VGPR=60 forced the compiler to interleave waitcnt between
// load pairs (LOADD macro consumed each pair immediately) -> ~2 loads in
// flight -> serialized HBM latency (~16us per block). Fix: issue ALL 29
// float4 loads into explicit register arrays BEFORE any consumption.

#define SD 65536LL      // d stride = H*W
#define SC 4194304LL    // channel stride = D*H*W

__global__ __launch_bounds__(256) void vort_dense(
    const float* __restrict__ preds, const float* __restrict__ targs,
    const float* __restrict__ masks, double* __restrict__ acc)
{
    const int lane = threadIdx.x & 63;
    const int wv   = threadIdx.x >> 6;
    int blk = blockIdx.x;
    const int tile = blk & 63; blk >>= 6;       // 64 h-tiles of 4 rows
    const int d = blk % 62 + 1; blk /= 62;      // interior d 1..62
    const int b = blk;                          // 0..1
    const int h = 1 + tile * 4 + wv;            // one row per wave
    const int w0 = lane << 2;                   // 4 w per lane, full 256 row

    float norm = 0.0f, cnt = 0.0f;

    if (h <= 254) {   // wave-uniform guard (tile 63 waves 2,3 out of range)
        const long long mbase = (long long)b * SC + (long long)d * SD
                              + (long long)h * 256 + w0;
        const long long b1 = ((long long)(b * 4 + 1) * 64 + d) * SD
                           + (long long)h * 256 + w0;
        const long long b2 = b1 + SC;
        const long long b3 = b2 + SC;

        // ---- issue ALL loads first: 10 pred + 10 targ + 9 mask float4 ----
        long long voff[10];
        voff[0] = b1 - SD;  voff[1] = b1 + SD;   // u d-/d+
        voff[2] = b1 - 256; voff[3] = b1 + 256;  // u h-/h+
        voff[4] = b2 - SD;  voff[5] = b2 + SD;   // v d-/d+
        voff[6] = b2;                             // v center
        voff[7] = b3 - 256; voff[8] = b3 + 256;  // w h-/h+
        voff[9] = b3;                             // w center

        float4 P[10], T[10], Mv[9];
        #pragma unroll
        for (int i = 0; i < 10; ++i) P[i] = *(const float4*)(preds + voff[i]);
        #pragma unroll
        for (int i = 0; i < 10; ++i) T[i] = *(const float4*)(targs + voff[i]);
        #pragma unroll
        for (int r = 0; r < 9; ++r) {
            const int dd = r / 3 - 1, dh = r % 3 - 1;
            Mv[r] = *(const float4*)(masks + mbase + (long long)dd * SD
                                     + (long long)dh * 256);
        }

        // ---- consume: diffs, mask min, shuffle edges, per-cell norm ----
        float Df[10][4];
        #pragma unroll
        for (int i = 0; i < 10; ++i) {
            Df[i][0] = P[i].x - T[i].x; Df[i][1] = P[i].y - T[i].y;
            Df[i][2] = P[i].z - T[i].z; Df[i][3] = P[i].w - T[i].w;
        }
        float4 M = Mv[0];
        #pragma unroll
        for (int r = 1; r < 9; ++r) {
            M.x = fminf(M.x, Mv[r].x); M.y = fminf(M.y, Mv[r].y);
            M.z = fminf(M.z, Mv[r].z); M.w = fminf(M.w, Mv[r].w);
        }

        const float vL = __shfl_up(Df[6][3], 1, 64);
        const float vR = __shfl_down(Df[6][0], 1, 64);
        const float wL = __shfl_up(Df[9][3], 1, 64);
        const float wR = __shfl_down(Df[9][0], 1, 64);
        const float ML = __shfl_up(M.w, 1, 64);
        const float MR = __shfl_down(M.x, 1, 64);

        const float vv[6] = { vL, Df[6][0], Df[6][1], Df[6][2], Df[6][3], vR };
        const float ww[6] = { wL, Df[9][0], Df[9][1], Df[9][2], Df[9][3], wR };
        const float Mm[6] = { ML, M.x, M.y, M.z, M.w, MR };

        #pragma unroll
        for (int j = 0; j < 4; ++j) {
            const int wc = w0 + j;
            const float keepv = fminf(fminf(Mm[j], Mm[j + 1]), Mm[j + 2]);
            const bool valid = (wc >= 1) && (wc <= 254) && (keepv > 0.5f);
            const float wx = (Df[8][j] - Df[7][j]) - (Df[5][j] - Df[4][j]);
            const float wy = (Df[1][j] - Df[0][j]) - (ww[j + 2] - ww[j]);
            const float wz = (vv[j + 2] - vv[j]) - (Df[3][j] - Df[2][j]);
            const float n = sqrtf(wx * wx + wy * wy + wz * wz);
            norm += valid ? n : 0.0f;
            cnt  += valid ? 1.0f : 0.0f;
        }
    }

    // ---- reduction: wave shuffle -> LDS across 4 waves -> global atomic ----
    #pragma unroll
    for (int off = 32; off > 0; off >>= 1) {
        norm += __shfl_down(norm, off, 64);
        cnt  += __shfl_down(cnt,  off, 64);
    }
    __shared__ float ssum[4], scnt[4];
    if (lane == 0) { ssum[wv] = norm; scnt[wv] = cnt; }
    __syncthreads();
    if (threadIdx.x == 0) {
        const float s = ssum[0] + ssum[1] + ssum[2] + ssum[3];
        const float c = scnt[0] + scnt[1] + scnt[2] + scnt[3];
        atomicAdd(&acc[0], (double)s);
        atomicAdd(&acc[1], (double)c);
    }
}

__global__ void finalize_kernel(const double* __restrict__ acc, float* __restrict__ out)
{
    const double c = acc[1];
    out[0] = (c != 0.0) ? (float)(acc[0] / c) : 0.0f;
}

extern "C" void kernel_launch(void* const* d_in, const int* in_sizes, int n_in,
                              void* d_out, int out_size, void* d_ws, size_t ws_size,
                              hipStream_t stream)
{
    const float* preds = (const float*)d_in[0];
    const float* targs = (const float*)d_in[1];
    const float* masks = (const float*)d_in[2];
    float* out = (float*)d_out;
    double* acc = (double*)d_ws;

    hipMemsetAsync(d_ws, 0, 2 * sizeof(double), stream);

    const int nblocks = 2 * 62 * 64;   // (b, d-1, h-tile)
    vort_dense<<<nblocks, 256, 0, stream>>>(preds, targs, masks, acc);
    finalize_kernel<<<1, 1, 0, stream>>>(acc, out);
}